// Round 1
// baseline (180.373 us; speedup 1.0000x reference)
//
#include <hip/hip_runtime.h>

#define NN 8192

typedef __bf16 bf16x8 __attribute__((ext_vector_type(8)));
typedef float f32x4 __attribute__((ext_vector_type(4)));
typedef unsigned short u16x8 __attribute__((ext_vector_type(8)));

#define GLOBAL_AS __attribute__((address_space(1)))
#define LDS_AS __attribute__((address_space(3)))

__device__ __forceinline__ unsigned short f2bf(float f) {
  unsigned int u = __builtin_bit_cast(unsigned int, f);
  u += 0x7FFFu + ((u >> 16) & 1u);   // RNE
  return (unsigned short)(u >> 16);
}
__device__ __forceinline__ float bf2f(unsigned short b) {
  unsigned int u = ((unsigned int)b) << 16;
  return __builtin_bit_cast(float, u);
}

// ---------------------------------------------------------------------------
// K1: prep.  Per block: one batch b, 64 nodes.  Computes
//   Yt[(b*64+fo)][j]  = bf16( x[b,j,:] @ W_neigh[:,fo] )   (transposed + XOR-swizzled in ws)
//   S  [b,j,fo]       = f32 ( x[b,j,:] @ W_self [:,fo] + b_self[fo] )  -> written into d_out
// ---------------------------------------------------------------------------
__global__ __launch_bounds__(256) void prep_kernel(
    const float* __restrict__ x, const float* __restrict__ Wself,
    const float* __restrict__ bself, const float* __restrict__ Wneigh,
    unsigned short* __restrict__ Yt, float* __restrict__ Sout) {
  __shared__ __align__(16) unsigned short xa[64 * 64];    // [j][k] swizzled
  __shared__ __align__(16) unsigned short bm[128 * 64];   // [n][k] swizzled; n<64: Wneigh, n>=64: Wself
  const int t = threadIdx.x;
  const int b = blockIdx.x >> 7;
  const int j0 = (blockIdx.x & 127) << 6;

  // stage W (transpose + convert + swizzle)
  {
    const float* Wsel = (t < 128) ? Wneigh : Wself;
    const int tt = t & 127;
    const int k = tt >> 1;
    const int c0 = (tt & 1) << 5;
    const int nbase = (t < 128) ? 0 : 64;
    const float4* src = (const float4*)(Wsel + k * 64 + c0);
#pragma unroll
    for (int q = 0; q < 8; ++q) {
      float4 v = src[q];
      int n0 = nbase + c0 + q * 4;
      int n;
      n = n0 + 0; bm[n * 64 + (k ^ ((n & 7) << 3))] = f2bf(v.x);
      n = n0 + 1; bm[n * 64 + (k ^ ((n & 7) << 3))] = f2bf(v.y);
      n = n0 + 2; bm[n * 64 + (k ^ ((n & 7) << 3))] = f2bf(v.z);
      n = n0 + 3; bm[n * 64 + (k ^ ((n & 7) << 3))] = f2bf(v.w);
    }
  }
  // stage x tile [64 j][64 k] -> bf16 swizzled
  {
    const int j = t >> 2, q = t & 3;
    const float* xrow = x + ((size_t)b * NN + j0 + j) * 64 + q * 16;
    float4 v0 = *(const float4*)(xrow + 0);
    float4 v1 = *(const float4*)(xrow + 4);
    float4 v2 = *(const float4*)(xrow + 8);
    float4 v3 = *(const float4*)(xrow + 12);
    u16x8 p0, p1;
    p0[0] = f2bf(v0.x); p0[1] = f2bf(v0.y); p0[2] = f2bf(v0.z); p0[3] = f2bf(v0.w);
    p0[4] = f2bf(v1.x); p0[5] = f2bf(v1.y); p0[6] = f2bf(v1.z); p0[7] = f2bf(v1.w);
    p1[0] = f2bf(v2.x); p1[1] = f2bf(v2.y); p1[2] = f2bf(v2.z); p1[3] = f2bf(v2.w);
    p1[4] = f2bf(v3.x); p1[5] = f2bf(v3.y); p1[6] = f2bf(v3.z); p1[7] = f2bf(v3.w);
    const int base = q * 16;
    const int sw = (j & 7) << 3;
    *(u16x8*)&xa[j * 64 + (base ^ sw)] = p0;
    *(u16x8*)&xa[j * 64 + ((base + 8) ^ sw)] = p1;
  }
  __syncthreads();

  const int lane = t & 63, w = t >> 6;
  const int rl = lane & 15, hi = lane >> 4;
  f32x4 acc[8];
#pragma unroll
  for (int i = 0; i < 8; ++i) acc[i] = (f32x4){0.f, 0.f, 0.f, 0.f};

#pragma unroll
  for (int ks = 0; ks < 2; ++ks) {
    const int r = w * 16 + rl;
    const int kel = ks * 32 + hi * 8;
    bf16x8 af = __builtin_bit_cast(bf16x8, *(u16x8*)&xa[r * 64 + (kel ^ ((r & 7) << 3))]);
#pragma unroll
    for (int nf = 0; nf < 8; ++nf) {
      const int n = nf * 16 + rl;
      bf16x8 bv = __builtin_bit_cast(bf16x8, *(u16x8*)&bm[n * 64 + (kel ^ ((n & 7) << 3))]);
      acc[nf] = __builtin_amdgcn_mfma_f32_16x16x32_bf16(af, bv, acc[nf], 0, 0, 0);
    }
  }
  // epilogue: C layout col=lane&15, row=(lane>>4)*4+reg
#pragma unroll
  for (int nf = 0; nf < 8; ++nf) {
    if (nf < 4) {
      const int n = nf * 16 + rl;           // Y column (local fo); global row = b*64+n
      unsigned short* yrow = Yt + (size_t)(b * 64 + n) * NN + j0;
      const int swn = (n & 7) << 3;
#pragma unroll
      for (int r = 0; r < 4; ++r) {
        const int jj = w * 16 + hi * 4 + r;
        yrow[jj ^ swn] = f2bf(acc[nf][r]);
      }
    } else {
      const int fo = (nf - 4) * 16 + rl;
      const float bsv = bself[fo];
#pragma unroll
      for (int r = 0; r < 4; ++r) {
        const int jj = w * 16 + hi * 4 + r;
        Sout[((size_t)b * NN + j0 + jj) * 64 + fo] = acc[nf][r] + bsv;
      }
    }
  }
}

// ---------------------------------------------------------------------------
// K2: big GEMM  C[i][n] = sum_j (adj[i][j]>0) * Yt[n][j],  n = b*64+fo.
// BM=64, BN=512, BK=64, K-split x2 (grid=256, 1 block/CU), 8 waves of 64x64.
// adj converted int32->bf16 during reg-staging; deg accumulated as by-product.
// Yt staged with global_load_lds (ws content pre-swizzled -> linear copy).
// ---------------------------------------------------------------------------
__global__ __launch_bounds__(512, 2) void gemm_kernel(
    const int* __restrict__ adj, const unsigned short* __restrict__ Yt,
    unsigned short* __restrict__ Cp, float* __restrict__ degp) {
  __shared__ __align__(16) unsigned short aL[2][64 * 64];    // 8KB x2
  __shared__ __align__(16) unsigned short yL[2][512 * 64];   // 64KB x2
  const int tid = threadIdx.x;
  const int lane = tid & 63, w = tid >> 6;
  const int mb = blockIdx.x >> 1, ksp = blockIdx.x & 1;
  const int i0 = mb << 6;
  const int kbase = ksp << 12;

  // A staging: thread -> (row ar, col-octet ac8), fixed across K-steps
  const int ar = tid >> 3, ac8 = tid & 7;
  const int* aptr = adj + (size_t)(i0 + ar) * NN + kbase + ac8 * 8;
  const int awidx = ar * 64 + ((ac8 * 8) ^ ((ar & 7) << 3));
  // Y staging: wave w stages rows [w*64, w*64+64), 8 rounds of 8 rows
  const int yn = (w << 6) + (lane >> 3);
  const unsigned short* ysrc0 = Yt + (size_t)yn * NN + kbase + (lane & 7) * 8;

  int degc = 0;
  f32x4 acc[4][4];
#pragma unroll
  for (int mf = 0; mf < 4; ++mf)
#pragma unroll
    for (int nf = 0; nf < 4; ++nf) acc[mf][nf] = (f32x4){0.f, 0.f, 0.f, 0.f};

  auto stageY = [&](int buf, int t) {
#pragma unroll
    for (int rr = 0; rr < 8; ++rr) {
      const unsigned short* g = ysrc0 + (size_t)rr * (8 * NN) + t * 64;
      __builtin_amdgcn_global_load_lds(
          (GLOBAL_AS void*)const_cast<unsigned short*>(g),
          (LDS_AS void*)&yL[buf][((w << 6) + rr * 8) * 64], 16, 0, 0);
    }
  };
  auto writeA = [&](int buf, int4 v0, int4 v1) {
    u16x8 p;
    p[0] = (v0.x > 0) ? 0x3F80 : 0; p[1] = (v0.y > 0) ? 0x3F80 : 0;
    p[2] = (v0.z > 0) ? 0x3F80 : 0; p[3] = (v0.w > 0) ? 0x3F80 : 0;
    p[4] = (v1.x > 0) ? 0x3F80 : 0; p[5] = (v1.y > 0) ? 0x3F80 : 0;
    p[6] = (v1.z > 0) ? 0x3F80 : 0; p[7] = (v1.w > 0) ? 0x3F80 : 0;
    degc += (v0.x > 0) + (v0.y > 0) + (v0.z > 0) + (v0.w > 0) +
            (v1.x > 0) + (v1.y > 0) + (v1.z > 0) + (v1.w > 0);
    *(u16x8*)&aL[buf][awidx] = p;
  };

  // prologue
  {
    int4 a0 = *(const int4*)(aptr);
    int4 a1 = *(const int4*)(aptr + 4);
    stageY(0, 0);
    writeA(0, a0, a1);
  }
  __syncthreads();

  const int rl = lane & 15, hi = lane >> 4;
  for (int t = 0; t < 64; ++t) {
    const int cur = t & 1, nxt = cur ^ 1;
    int4 b0, b1;
    if (t < 63) {
      b0 = *(const int4*)(aptr + (t + 1) * 64);
      b1 = *(const int4*)(aptr + (t + 1) * 64 + 4);
      stageY(nxt, t + 1);
    }
    // compute on buf[cur]
    bf16x8 af[2][4], bv[2][4];
#pragma unroll
    for (int ks = 0; ks < 2; ++ks) {
      const int kel = ks * 32 + hi * 8;
#pragma unroll
      for (int mf = 0; mf < 4; ++mf) {
        const int r = mf * 16 + rl;
        af[ks][mf] = __builtin_bit_cast(
            bf16x8, *(u16x8*)&aL[cur][r * 64 + (kel ^ ((r & 7) << 3))]);
      }
#pragma unroll
      for (int nf = 0; nf < 4; ++nf) {
        const int n = (w << 6) + nf * 16 + rl;
        bv[ks][nf] = __builtin_bit_cast(
            bf16x8, *(u16x8*)&yL[cur][n * 64 + (kel ^ ((n & 7) << 3))]);
      }
    }
#pragma unroll
    for (int ks = 0; ks < 2; ++ks)
#pragma unroll
      for (int mf = 0; mf < 4; ++mf)
#pragma unroll
        for (int nf = 0; nf < 4; ++nf)
          acc[mf][nf] = __builtin_amdgcn_mfma_f32_16x16x32_bf16(
              af[ks][mf], bv[ks][nf], acc[mf][nf], 0, 0, 0);
    if (t < 63) writeA(nxt, b0, b1);
    __syncthreads();
  }

  // deg: reduce over the 8 col-octet threads of each row (adjacent lanes)
  degc += __shfl_xor(degc, 1);
  degc += __shfl_xor(degc, 2);
  degc += __shfl_xor(degc, 4);
  if ((lane & 7) == 0) degp[ksp * NN + i0 + ar] = (float)degc;

  // C partial write (bf16)
#pragma unroll
  for (int mf = 0; mf < 4; ++mf)
#pragma unroll
    for (int nf = 0; nf < 4; ++nf) {
      const int col = (w << 6) + nf * 16 + rl;
#pragma unroll
      for (int r = 0; r < 4; ++r) {
        const int i = i0 + mf * 16 + hi * 4 + r;
        Cp[((size_t)ksp * NN + i) * 512 + col] = f2bf(acc[mf][nf][r]);
      }
    }
}

// ---------------------------------------------------------------------------
// K3: epilogue. One 64-lane wave per (b,i); lane = fo.
// v = relu(S + [deg>0]*(C/max(deg,1) + b_neigh)); LayerNorm over fo.
// S lives in d_out (written by prep); each lane reads then overwrites its own elem.
// ---------------------------------------------------------------------------
__global__ __launch_bounds__(256) void epi_kernel(
    const unsigned short* __restrict__ Cp, const float* __restrict__ degp,
    const float* S, const float* __restrict__ bneigh,
    const float* __restrict__ gamma, const float* __restrict__ beta,
    float* out) {
  const int lane = threadIdx.x & 63;
  const int wid = (blockIdx.x << 2) + (threadIdx.x >> 6);
  const int b = wid >> 13;
  const int i = wid & (NN - 1);
  const float deg = degp[i] + degp[NN + i];
  const float rdeg = 1.0f / fmaxf(deg, 1.0f);
  const size_t cidx = (size_t)i * 512 + b * 64 + lane;
  const float c = bf2f(Cp[cidx]) + bf2f(Cp[(size_t)NN * 512 + cidx]);
  const float sv = S[((size_t)b * NN + i) * 64 + lane];
  float v = sv + ((deg > 0.5f) ? (c * rdeg + bneigh[lane]) : 0.0f);
  v = fmaxf(v, 0.0f);
  float s1 = v, s2 = v * v;
#pragma unroll
  for (int m = 1; m < 64; m <<= 1) {
    s1 += __shfl_xor(s1, m);
    s2 += __shfl_xor(s2, m);
  }
  const float mu = s1 * 0.015625f;
  const float var = s2 * 0.015625f - mu * mu;
  const float o = (v - mu) * rsqrtf(var + 1e-5f) * gamma[lane] + beta[lane];
  out[((size_t)b * NN + i) * 64 + lane] = o;
}

extern "C" void kernel_launch(void* const* d_in, const int* in_sizes, int n_in,
                              void* d_out, int out_size, void* d_ws, size_t ws_size,
                              hipStream_t stream) {
  (void)in_sizes; (void)n_in; (void)out_size; (void)ws_size;
  const float* x      = (const float*)d_in[0];
  const int*   adj    = (const int*)d_in[1];
  const float* Wself  = (const float*)d_in[2];
  const float* bself  = (const float*)d_in[3];
  const float* Wneigh = (const float*)d_in[4];
  const float* bneigh = (const float*)d_in[5];
  const float* gamma  = (const float*)d_in[6];
  const float* beta   = (const float*)d_in[7];
  float* out = (float*)d_out;
  char* ws = (char*)d_ws;
  unsigned short* Yt = (unsigned short*)ws;                         //  8,388,608 B
  unsigned short* Cp = (unsigned short*)(ws + 8388608);             // 16,777,216 B
  float* degp = (float*)(ws + 8388608 + 16777216);                  //     65,536 B

  prep_kernel<<<dim3(1024), dim3(256), 0, stream>>>(x, Wself, bself, Wneigh, Yt, out);
  gemm_kernel<<<dim3(256), dim3(512), 0, stream>>>(adj, Yt, Cp, degp);
  epi_kernel<<<dim3(16384), dim3(256), 0, stream>>>(Cp, degp, out, bneigh, gamma, beta, out);
}

// Round 2
// 156.826 us; speedup vs baseline: 1.1501x; 1.1501x over previous
//
#include <hip/hip_runtime.h>

#define NN 8192

typedef __bf16 bf16x8 __attribute__((ext_vector_type(8)));
typedef float f32x4 __attribute__((ext_vector_type(4)));
typedef unsigned short u16x8 __attribute__((ext_vector_type(8)));

#define GLOBAL_AS __attribute__((address_space(1)))
#define LDS_AS __attribute__((address_space(3)))

__device__ __forceinline__ unsigned short f2bf(float f) {
  unsigned int u = __builtin_bit_cast(unsigned int, f);
  u += 0x7FFFu + ((u >> 16) & 1u);   // RNE
  return (unsigned short)(u >> 16);
}
__device__ __forceinline__ float bf2f(unsigned short b) {
  unsigned int u = ((unsigned int)b) << 16;
  return __builtin_bit_cast(float, u);
}

// ---------------------------------------------------------------------------
// K1: prep.  Per block: one batch b, 64 nodes.  Computes
//   Yt[(b*64+fo)][j]  = bf16( x[b,j,:] @ W_neigh[:,fo] )   (transposed + XOR-swizzled in ws)
//   S  [b,j,fo]       = f32 ( x[b,j,:] @ W_self [:,fo] + b_self[fo] )  -> written into d_out
// ---------------------------------------------------------------------------
__global__ __launch_bounds__(256) void prep_kernel(
    const float* __restrict__ x, const float* __restrict__ Wself,
    const float* __restrict__ bself, const float* __restrict__ Wneigh,
    unsigned short* __restrict__ Yt, float* __restrict__ Sout) {
  __shared__ __align__(16) unsigned short xa[64 * 64];    // [j][k] swizzled
  __shared__ __align__(16) unsigned short bm[128 * 64];   // [n][k] swizzled; n<64: Wneigh, n>=64: Wself
  const int t = threadIdx.x;
  const int b = blockIdx.x >> 7;
  const int j0 = (blockIdx.x & 127) << 6;

  // stage W (transpose + convert + swizzle)
  {
    const float* Wsel = (t < 128) ? Wneigh : Wself;
    const int tt = t & 127;
    const int k = tt >> 1;
    const int c0 = (tt & 1) << 5;
    const int nbase = (t < 128) ? 0 : 64;
    const float4* src = (const float4*)(Wsel + k * 64 + c0);
#pragma unroll
    for (int q = 0; q < 8; ++q) {
      float4 v = src[q];
      int n0 = nbase + c0 + q * 4;
      int n;
      n = n0 + 0; bm[n * 64 + (k ^ ((n & 7) << 3))] = f2bf(v.x);
      n = n0 + 1; bm[n * 64 + (k ^ ((n & 7) << 3))] = f2bf(v.y);
      n = n0 + 2; bm[n * 64 + (k ^ ((n & 7) << 3))] = f2bf(v.z);
      n = n0 + 3; bm[n * 64 + (k ^ ((n & 7) << 3))] = f2bf(v.w);
    }
  }
  // stage x tile [64 j][64 k] -> bf16 swizzled
  {
    const int j = t >> 2, q = t & 3;
    const float* xrow = x + ((size_t)b * NN + j0 + j) * 64 + q * 16;
    float4 v0 = *(const float4*)(xrow + 0);
    float4 v1 = *(const float4*)(xrow + 4);
    float4 v2 = *(const float4*)(xrow + 8);
    float4 v3 = *(const float4*)(xrow + 12);
    u16x8 p0, p1;
    p0[0] = f2bf(v0.x); p0[1] = f2bf(v0.y); p0[2] = f2bf(v0.z); p0[3] = f2bf(v0.w);
    p0[4] = f2bf(v1.x); p0[5] = f2bf(v1.y); p0[6] = f2bf(v1.z); p0[7] = f2bf(v1.w);
    p1[0] = f2bf(v2.x); p1[1] = f2bf(v2.y); p1[2] = f2bf(v2.z); p1[3] = f2bf(v2.w);
    p1[4] = f2bf(v3.x); p1[5] = f2bf(v3.y); p1[6] = f2bf(v3.z); p1[7] = f2bf(v3.w);
    const int base = q * 16;
    const int sw = (j & 7) << 3;
    *(u16x8*)&xa[j * 64 + (base ^ sw)] = p0;
    *(u16x8*)&xa[j * 64 + ((base + 8) ^ sw)] = p1;
  }
  __syncthreads();

  const int lane = t & 63, w = t >> 6;
  const int rl = lane & 15, hi = lane >> 4;
  f32x4 acc[8];
#pragma unroll
  for (int i = 0; i < 8; ++i) acc[i] = (f32x4){0.f, 0.f, 0.f, 0.f};

#pragma unroll
  for (int ks = 0; ks < 2; ++ks) {
    const int r = w * 16 + rl;
    const int kel = ks * 32 + hi * 8;
    bf16x8 af = __builtin_bit_cast(bf16x8, *(u16x8*)&xa[r * 64 + (kel ^ ((r & 7) << 3))]);
#pragma unroll
    for (int nf = 0; nf < 8; ++nf) {
      const int n = nf * 16 + rl;
      bf16x8 bv = __builtin_bit_cast(bf16x8, *(u16x8*)&bm[n * 64 + (kel ^ ((n & 7) << 3))]);
      acc[nf] = __builtin_amdgcn_mfma_f32_16x16x32_bf16(af, bv, acc[nf], 0, 0, 0);
    }
  }
  // epilogue: C layout col=lane&15, row=(lane>>4)*4+reg
#pragma unroll
  for (int nf = 0; nf < 8; ++nf) {
    if (nf < 4) {
      const int n = nf * 16 + rl;           // Y column (local fo); global row = b*64+n
      unsigned short* yrow = Yt + (size_t)(b * 64 + n) * NN + j0;
      const int swn = (n & 7) << 3;
#pragma unroll
      for (int r = 0; r < 4; ++r) {
        const int jj = w * 16 + hi * 4 + r;
        yrow[jj ^ swn] = f2bf(acc[nf][r]);
      }
    } else {
      const int fo = (nf - 4) * 16 + rl;
      const float bsv = bself[fo];
#pragma unroll
      for (int r = 0; r < 4; ++r) {
        const int jj = w * 16 + hi * 4 + r;
        Sout[((size_t)b * NN + j0 + jj) * 64 + fo] = acc[nf][r] + bsv;
      }
    }
  }
}

// ---------------------------------------------------------------------------
// K2: big GEMM  C[i][n] = sum_j (adj[i][j]>0) * Yt[n][j],  n = b*64+fo.
// BM=64, BN=256, BK=64.  Grid = 128 mb x 2 nb x 2 ksp = 512 blocks =
// 2 blocks/CU (80 KB LDS each) so sibling blocks overlap each other's
// barrier drains.  4 waves/block, each wave owns a 64x64 output tile.
// adj converted int32->bf16 during reg-staging (prefetched 2 K-steps ahead);
// deg accumulated as by-product.  Yt staged with global_load_lds (ws content
// pre-swizzled -> linear copy).  XCD-bijective swizzle groups blocks so each
// XCD reads one 2 MB Yt slice (L2-resident).
// ---------------------------------------------------------------------------
__global__ __launch_bounds__(256, 2) void gemm_kernel(
    const int* __restrict__ adj, const unsigned short* __restrict__ Yt,
    unsigned short* __restrict__ Cp, float* __restrict__ degp) {
  __shared__ __align__(16) unsigned short aL[2][64 * 64];    //  8 KB x2
  __shared__ __align__(16) unsigned short yL[2][256 * 64];   // 32 KB x2
  const int tid = threadIdx.x;
  const int lane = tid & 63, w = tid >> 6;
  // XCD swizzle: 512 blocks, round-robin -> XCD (bid&7); give each XCD one
  // contiguous 64-block chunk = one (ksp,nb) Yt slice + contiguous mb range.
  const int nid = ((blockIdx.x & 7) << 6) + (blockIdx.x >> 3);
  const int ksp = nid >> 8;
  const int nb = (nid >> 7) & 1;
  const int mb = nid & 127;
  const int i0 = mb << 6;
  const int kbase = ksp << 12;
  const int ncol0 = nb << 8;

  // A staging: thread -> (row ar, 16-int group ac16), 64 B/thread/K-step
  const int ar = tid >> 2, ac16 = tid & 3;
  const int* aptr = adj + (size_t)(i0 + ar) * NN + kbase + ac16 * 16;
  const int asw = (ar & 7) << 3;
  const int aw0 = ar * 64 + ((ac16 * 16) ^ asw);
  const int aw1 = ar * 64 + ((ac16 * 16 + 8) ^ asw);
  // Y staging: wave w stages local rows [w*64, w*64+64), 8 rounds of 8 rows
  const int yn = ncol0 + (w << 6) + (lane >> 3);
  const unsigned short* ysrc0 = Yt + (size_t)yn * NN + kbase + (lane & 7) * 8;

  int degc = 0;
  f32x4 acc[4][4];
#pragma unroll
  for (int mf = 0; mf < 4; ++mf)
#pragma unroll
    for (int nf = 0; nf < 4; ++nf) acc[mf][nf] = (f32x4){0.f, 0.f, 0.f, 0.f};

  const int rl = lane & 15, hi = lane >> 4;
  const int fsw = (rl & 7) << 3;   // frag-row swizzle (row&7 == rl&7 for all frags)

#define LOADA(dst, t)                                             \
  {                                                               \
    const int4* p_ = (const int4*)(aptr + (t) * 64);              \
    dst[0] = p_[0]; dst[1] = p_[1]; dst[2] = p_[2]; dst[3] = p_[3]; \
  }

#define WRITEA(buf, L)                                                        \
  {                                                                           \
    u16x8 p0_, p1_;                                                           \
    p0_[0] = (L[0].x > 0) ? 0x3F80 : 0; p0_[1] = (L[0].y > 0) ? 0x3F80 : 0;   \
    p0_[2] = (L[0].z > 0) ? 0x3F80 : 0; p0_[3] = (L[0].w > 0) ? 0x3F80 : 0;   \
    p0_[4] = (L[1].x > 0) ? 0x3F80 : 0; p0_[5] = (L[1].y > 0) ? 0x3F80 : 0;   \
    p0_[6] = (L[1].z > 0) ? 0x3F80 : 0; p0_[7] = (L[1].w > 0) ? 0x3F80 : 0;   \
    p1_[0] = (L[2].x > 0) ? 0x3F80 : 0; p1_[1] = (L[2].y > 0) ? 0x3F80 : 0;   \
    p1_[2] = (L[2].z > 0) ? 0x3F80 : 0; p1_[3] = (L[2].w > 0) ? 0x3F80 : 0;   \
    p1_[4] = (L[3].x > 0) ? 0x3F80 : 0; p1_[5] = (L[3].y > 0) ? 0x3F80 : 0;   \
    p1_[6] = (L[3].z > 0) ? 0x3F80 : 0; p1_[7] = (L[3].w > 0) ? 0x3F80 : 0;   \
    degc += (L[0].x > 0) + (L[0].y > 0) + (L[0].z > 0) + (L[0].w > 0) +       \
            (L[1].x > 0) + (L[1].y > 0) + (L[1].z > 0) + (L[1].w > 0) +       \
            (L[2].x > 0) + (L[2].y > 0) + (L[2].z > 0) + (L[2].w > 0) +       \
            (L[3].x > 0) + (L[3].y > 0) + (L[3].z > 0) + (L[3].w > 0);        \
    *(u16x8*)&aL[buf][aw0] = p0_;                                             \
    *(u16x8*)&aL[buf][aw1] = p1_;                                             \
  }

#define STAGEY(buf, t)                                                        \
  {                                                                           \
    _Pragma("unroll")                                                         \
    for (int rr_ = 0; rr_ < 8; ++rr_) {                                       \
      const unsigned short* g_ = ysrc0 + (size_t)rr_ * (8 * NN) + (t) * 64;   \
      __builtin_amdgcn_global_load_lds(                                       \
          (GLOBAL_AS void*)const_cast<unsigned short*>(g_),                   \
          (LDS_AS void*)&yL[buf][((w << 6) + rr_ * 8) * 64], 16, 0, 0);       \
    }                                                                         \
  }

#define COMPUTE(buf)                                                          \
  {                                                                           \
    _Pragma("unroll")                                                         \
    for (int ks_ = 0; ks_ < 2; ++ks_) {                                       \
      const int kel_ = (ks_ * 32 + hi * 8) ^ fsw;                             \
      bf16x8 af_[4], bv_[4];                                                  \
      _Pragma("unroll")                                                       \
      for (int mf_ = 0; mf_ < 4; ++mf_)                                       \
        af_[mf_] = __builtin_bit_cast(                                        \
            bf16x8, *(u16x8*)&aL[buf][(mf_ * 16 + rl) * 64 + kel_]);          \
      _Pragma("unroll")                                                       \
      for (int nf_ = 0; nf_ < 4; ++nf_)                                       \
        bv_[nf_] = __builtin_bit_cast(                                        \
            bf16x8, *(u16x8*)&yL[buf][((w << 6) + nf_ * 16 + rl) * 64 + kel_]); \
      _Pragma("unroll")                                                       \
      for (int mf_ = 0; mf_ < 4; ++mf_)                                       \
        _Pragma("unroll")                                                     \
        for (int nf_ = 0; nf_ < 4; ++nf_)                                     \
          acc[mf_][nf_] = __builtin_amdgcn_mfma_f32_16x16x32_bf16(            \
              af_[mf_], bv_[nf_], acc[mf_][nf_], 0, 0, 0);                    \
    }                                                                         \
  }

  int4 La[4], Lb[4];
  // prologue: A(t=0) -> buf0; prefetch A(t=1); Y(t=0) -> buf0
  LOADA(La, 0);
  WRITEA(0, La);
  LOADA(La, 1);
  STAGEY(0, 0);
  __syncthreads();

  for (int t2 = 0; t2 < 64; t2 += 2) {
    // ---- even step: compute buf0 (t = t2) ----
    STAGEY(1, t2 + 1);
    if (t2 + 2 < 64) LOADA(Lb, t2 + 2);
    COMPUTE(0);
    WRITEA(1, La);      // A for t2+1 (loaded one step earlier)
    __syncthreads();
    // ---- odd step: compute buf1 (t = t2+1) ----
    if (t2 + 2 < 64) STAGEY(0, t2 + 2);
    if (t2 + 3 < 64) LOADA(La, t2 + 3);
    COMPUTE(1);
    if (t2 + 2 < 64) WRITEA(0, Lb);
    __syncthreads();
  }

  // deg: reduce over the 4 col-group threads of each row (adjacent lanes);
  // nb==0 and nb==1 blocks would compute identical deg -> only nb==0 writes.
  degc += __shfl_xor(degc, 1);
  degc += __shfl_xor(degc, 2);
  if (nb == 0 && (lane & 3) == 0) degp[ksp * NN + i0 + ar] = (float)degc;

  // C partial write (bf16)
#pragma unroll
  for (int mf = 0; mf < 4; ++mf)
#pragma unroll
    for (int nf = 0; nf < 4; ++nf) {
      const int col = ncol0 + (w << 6) + nf * 16 + rl;
#pragma unroll
      for (int r = 0; r < 4; ++r) {
        const int i = i0 + mf * 16 + hi * 4 + r;
        Cp[((size_t)ksp * NN + i) * 512 + col] = f2bf(acc[mf][nf][r]);
      }
    }
#undef LOADA
#undef WRITEA
#undef STAGEY
#undef COMPUTE
}

// ---------------------------------------------------------------------------
// K3: epilogue. One 64-lane wave per (b,i); lane = fo.
// v = relu(S + [deg>0]*(C/max(deg,1) + b_neigh)); LayerNorm over fo.
// S lives in d_out (written by prep); each lane reads then overwrites its own elem.
// ---------------------------------------------------------------------------
__global__ __launch_bounds__(256) void epi_kernel(
    const unsigned short* __restrict__ Cp, const float* __restrict__ degp,
    const float* S, const float* __restrict__ bneigh,
    const float* __restrict__ gamma, const float* __restrict__ beta,
    float* out) {
  const int lane = threadIdx.x & 63;
  const int wid = (blockIdx.x << 2) + (threadIdx.x >> 6);
  const int b = wid >> 13;
  const int i = wid & (NN - 1);
  const float deg = degp[i] + degp[NN + i];
  const float rdeg = 1.0f / fmaxf(deg, 1.0f);
  const size_t cidx = (size_t)i * 512 + b * 64 + lane;
  const float c = bf2f(Cp[cidx]) + bf2f(Cp[(size_t)NN * 512 + cidx]);
  const float sv = S[((size_t)b * NN + i) * 64 + lane];
  float v = sv + ((deg > 0.5f) ? (c * rdeg + bneigh[lane]) : 0.0f);
  v = fmaxf(v, 0.0f);
  float s1 = v, s2 = v * v;
#pragma unroll
  for (int m = 1; m < 64; m <<= 1) {
    s1 += __shfl_xor(s1, m);
    s2 += __shfl_xor(s2, m);
  }
  const float mu = s1 * 0.015625f;
  const float var = s2 * 0.015625f - mu * mu;
  const float o = (v - mu) * rsqrtf(var + 1e-5f) * gamma[lane] + beta[lane];
  out[((size_t)b * NN + i) * 64 + lane] = o;
}

extern "C" void kernel_launch(void* const* d_in, const int* in_sizes, int n_in,
                              void* d_out, int out_size, void* d_ws, size_t ws_size,
                              hipStream_t stream) {
  (void)in_sizes; (void)n_in; (void)out_size; (void)ws_size;
  const float* x      = (const float*)d_in[0];
  const int*   adj    = (const int*)d_in[1];
  const float* Wself  = (const float*)d_in[2];
  const float* bself  = (const float*)d_in[3];
  const float* Wneigh = (const float*)d_in[4];
  const float* bneigh = (const float*)d_in[5];
  const float* gamma  = (const float*)d_in[6];
  const float* beta   = (const float*)d_in[7];
  float* out = (float*)d_out;
  char* ws = (char*)d_ws;
  unsigned short* Yt = (unsigned short*)ws;                         //  8,388,608 B
  unsigned short* Cp = (unsigned short*)(ws + 8388608);             // 16,777,216 B
  float* degp = (float*)(ws + 8388608 + 16777216);                  //     65,536 B

  prep_kernel<<<dim3(1024), dim3(256), 0, stream>>>(x, Wself, bself, Wneigh, Yt, out);
  gemm_kernel<<<dim3(512), dim3(256), 0, stream>>>(adj, Yt, Cp, degp);
  epi_kernel<<<dim3(16384), dim3(256), 0, stream>>>(Cp, degp, out, bneigh, gamma, beta, out);
}